// Round 2
// baseline (2222.212 us; speedup 1.0000x reference)
//
#include <hip/hip_runtime.h>
#include <cstdint>

// ---------------- constants ----------------
// B=256, DIM=64, K=3, NQ=8, VOCAB=50
// E1 = 36928 (= 64 + 36864), E2 = 8256 (= 64 + 8192)
// q_rep column map (45184 per sample):
//   [0,36864):      cw[oc][ic][tap]  (emb1 cols)
//   [36864,36928):  cb[oc]           (emb1 cols)
//   [36928,45120):  pw[o][d]         (emb2 cols 0..8192)
//   [45120,45184):  pb[o]            (emb2 cols 8192..8256)
// K4 gathers these on the fly (no q_rep materialization).

// ---------------- K0: softmaxes ----------------
__global__ void k0_softmax(const float* __restrict__ alpha,
                           const float* __restrict__ tau0,
                           const float* __restrict__ tau1,
                           float* __restrict__ soft) {
  int t = threadIdx.x;
  if (t < 3) {
    float m = -1e30f;
    for (int j = 0; j < 8; j++) m = fmaxf(m, alpha[t*8+j]);
    float e[8]; float s = 0.f;
    #pragma unroll
    for (int j = 0; j < 8; j++) { e[j] = expf(alpha[t*8+j]-m); s += e[j]; }
    #pragma unroll
    for (int j = 0; j < 8; j++) soft[t*8+j] = e[j]/s;
  } else if (t >= 4 && t < 7) {
    int i = t-4; int n = i+2;
    float m = -1e30f;
    for (int j = 0; j < n; j++) m = fmaxf(m, tau0[i*4+j]);
    float e[4]; float s = 0.f;
    for (int j = 0; j < n; j++) { e[j] = expf(tau0[i*4+j]-m); s += e[j]; }
    for (int j = 0; j < 4; j++) soft[24+i*4+j] = (j<n) ? e[j]/s : 0.f;
  } else if (t >= 8 && t < 11) {
    int i = t-8; int n = i+2;
    float m = -1e30f;
    for (int j = 0; j < n; j++) m = fmaxf(m, tau1[i*4+j]);
    float e[4]; float s = 0.f;
    for (int j = 0; j < n; j++) { e[j] = expf(tau1[i*4+j]-m); s += e[j]; }
    for (int j = 0; j < 4; j++) soft[36+i*4+j] = (j<n) ? e[j]/s : 0.f;
  }
}

// ---------------- Kpre: transpose w_s1 -> w1t[ic][tap][oc] ----------------
__global__ __launch_bounds__(256) void kpre_wt(const float* __restrict__ w1,
                                               float* __restrict__ w1t) {
  int i = blockIdx.x*256 + threadIdx.x;   // < 36864
  int oc = i / 576; int rem = i - oc*576; int ic = rem / 9; int tap = rem - ic*9;
  w1t[(ic*9 + tap)*64 + oc] = w1[i];
}

// ---------------- K1: stem conv1 (3->64, 64x64, pad1) + relu + pool -> (b,64,32,32)
__global__ __launch_bounds__(256) void k1_stem1(
    const float* __restrict__ image, const float* __restrict__ w0,
    const float* __restrict__ b0, float* __restrict__ x1) {
  __shared__ float img[3*66*66];   // padded planes
  __shared__ float wls[64*27];
  __shared__ float bls[64];
  int bx = blockIdx.x;             // 512 = b*2 + half
  int b = bx >> 1, half = bx & 1;
  int t = threadIdx.x;
  for (int i = t; i < 3*66*66; i += 256) img[i] = 0.f;
  for (int i = t; i < 1728; i += 256) wls[i] = w0[i];
  if (t < 64) bls[t] = b0[t];
  __syncthreads();
  const float* ib = image + (size_t)b*3*4096;
  for (int i = t*4; i < 12288; i += 1024) {
    float4 v = *(const float4*)&ib[i];
    int c = i >> 12, r = (i >> 6) & 63, x = i & 63;
    float* dst = &img[c*4356 + (r+1)*66 + (x+1)];
    dst[0]=v.x; dst[1]=v.y; dst[2]=v.z; dst[3]=v.w;
  }
  __syncthreads();
  int py = t >> 3, px0 = (t & 7) * 4;
  float* outb = x1 + ((size_t)b*64 + half*32)*1024;
  for (int oc = 0; oc < 32; oc++) {
    int oco = half*32 + oc;
    float val[2][8];
    #pragma unroll
    for (int r = 0; r < 2; r++)
      #pragma unroll
      for (int c = 0; c < 8; c++) val[r][c] = 0.f;
    #pragma unroll
    for (int ic = 0; ic < 3; ic++) {
      float wn[4][10];
      #pragma unroll
      for (int r = 0; r < 4; r++) {
        #pragma unroll
        for (int c = 0; c < 10; c += 2) {
          float2 v = *(const float2*)&img[ic*4356 + (2*py+r)*66 + 2*px0 + c];
          wn[r][c] = v.x; wn[r][c+1] = v.y;
        }
      }
      const float* wp = &wls[oco*27 + ic*9];
      float w9[9];
      #pragma unroll
      for (int j = 0; j < 9; j++) w9[j] = wp[j];
      #pragma unroll
      for (int dy = 0; dy < 3; dy++)
        #pragma unroll
        for (int dx = 0; dx < 3; dx++) {
          float w = w9[dy*3+dx];
          #pragma unroll
          for (int r = 0; r < 2; r++)
            #pragma unroll
            for (int c = 0; c < 8; c++)
              val[r][c] = fmaf(w, wn[r+dy][c+dx], val[r][c]);
        }
    }
    float bias = bls[oco];
    float4 o4;
    float* po = (float*)&o4;
    #pragma unroll
    for (int c = 0; c < 4; c++) {
      float m = fmaxf(fmaxf(val[0][2*c], val[0][2*c+1]),
                      fmaxf(val[1][2*c], val[1][2*c+1]));
      po[c] = fmaxf(m + bias, 0.f);
    }
    *(float4*)&outb[(size_t)oc*1024 + py*32 + px0] = o4;
  }
}

// ---------------- K2: stem conv2 (64->64, 32x32, pad1) + relu + pool -> h1 (b,64,16,16)
// weights read uniformly from global w1t (scalarizable); LDS holds image tile only.
__global__ __launch_bounds__(256) void k2_stem2(
    const float* __restrict__ x1, const float* __restrict__ w1t,
    const float* __restrict__ b1, float* __restrict__ h1) {
  __shared__ float inp[8*34*34];   // 9248 floats, padded planes (chunk of 8 in-ch)
  int bx = blockIdx.x;
  // XCD-aware remap: same-sample blocks share bx%8 (same XCD under round-robin)
  int b  = (bx & 7)*32 + ((bx >> 3) & 31);
  int ocb = (bx >> 8) * 16;        // 4 groups of 16 out-channels
  int t = threadIdx.x;
  for (int i = t; i < 9248; i += 256) inp[i] = 0.f;
  int py = t >> 4, px = t & 15;
  float val[16][2][2];
  #pragma unroll
  for (int o = 0; o < 16; o++) { val[o][0][0]=0.f; val[o][0][1]=0.f; val[o][1][0]=0.f; val[o][1][1]=0.f; }
  const float* xb = x1 + (size_t)b*65536;
  for (int icc = 0; icc < 8; icc++) {
    __syncthreads();   // protect previous chunk reads (and initial zero) before restage
    for (int i = t*4; i < 8192; i += 1024) {
      int icl = i >> 10;
      float4 v = *(const float4*)&xb[(size_t)(icc*8+icl)*1024 + (i & 1023)];
      float* dst = &inp[icl*1156 + (((i>>5)&31)+1)*34 + (i&31) + 1];
      dst[0]=v.x; dst[1]=v.y; dst[2]=v.z; dst[3]=v.w;
    }
    __syncthreads();
    for (int icl = 0; icl < 8; icl++) {
      int ic = icc*8 + icl;
      float wn[4][4];
      #pragma unroll
      for (int r = 0; r < 4; r++) {
        float2 v0 = *(const float2*)&inp[icl*1156 + (2*py+r)*34 + 2*px];
        float2 v1 = *(const float2*)&inp[icl*1156 + (2*py+r)*34 + 2*px + 2];
        wn[r][0]=v0.x; wn[r][1]=v0.y; wn[r][2]=v1.x; wn[r][3]=v1.y;
      }
      const float* wrow = w1t + (size_t)ic*576 + ocb;   // uniform address
      #pragma unroll
      for (int tap = 0; tap < 9; tap++) {
        const float4* wp = (const float4*)(wrow + tap*64);
        float4 wv0 = wp[0], wv1 = wp[1], wv2 = wp[2], wv3 = wp[3];
        float w16[16] = {wv0.x,wv0.y,wv0.z,wv0.w, wv1.x,wv1.y,wv1.z,wv1.w,
                         wv2.x,wv2.y,wv2.z,wv2.w, wv3.x,wv3.y,wv3.z,wv3.w};
        int dy = tap / 3, dx = tap - dy*3;
        #pragma unroll
        for (int oc = 0; oc < 16; oc++) {
          float w = w16[oc];
          #pragma unroll
          for (int r = 0; r < 2; r++)
            #pragma unroll
            for (int c = 0; c < 2; c++)
              val[oc][r][c] = fmaf(w, wn[r+dy][c+dx], val[oc][r][c]);
        }
      }
    }
  }
  float* hb = h1 + ((size_t)b*64 + ocb)*256;
  #pragma unroll
  for (int oc = 0; oc < 16; oc++) {
    float m = fmaxf(fmaxf(val[oc][0][0], val[oc][0][1]),
                    fmaxf(val[oc][1][0], val[oc][1][1]));
    hb[(size_t)oc*256 + py*16 + px] = fmaxf(m + b1[ocb+oc], 0.f);
  }
}

// ---------------- K4: fused module (gather + blend -> proj -> per-sample conv) ----
// one block per sample, 512 threads; dynamic LDS 110592 B; q_rep gathered on the fly.
__global__ __launch_bounds__(512) void k4_module(
    const int* __restrict__ question, const float* __restrict__ emb1,
    const float* __restrict__ emb2, const float* __restrict__ soft,
    const float* __restrict__ h1, const float* __restrict__ h2,
    const float* __restrict__ h3, float* __restrict__ hout, int iter) {
  extern __shared__ float sm[];
  float* inp  = sm;            // [64*256] phase A (aliased by ppad in phase B)
  float* pwt  = sm + 16384;    // [4096]  pw_t[d_local][o]
  float* ppad = sm;            // [64][18][20] = 23040 phase B
  float* cwt  = sm + 23040;    // [4608]  cw_t[icl][tap][oc]
  __shared__ float cbpb[128];  // cb[64] | pb[64]
  int b = blockIdx.x;
  int t = threadIdx.x;
  int og = t >> 6, pg = t & 63;
  int o8 = og*8, p4 = pg*4;
  int y = pg >> 2, x0 = (pg & 3)*4;
  size_t hb = (size_t)b*16384;

  int idx[8]; float a[8];
  #pragma unroll
  for (int q = 0; q < 8; q++) { idx[q] = question[b*8+q]; a[q] = soft[iter*8+q]; }

  // stage cb / pb (covered by the first __syncthreads below)
  if (t < 128) {
    const float* base; size_t stride; int src;
    if (t < 64) { base = emb1; stride = 36928; src = 36864 + t; }
    else        { base = emb2; stride = 8256;  src = 8192 + (t - 64); }
    float s = 0.f;
    #pragma unroll
    for (int q = 0; q < 8; q++) s = fmaf(a[q], base[(size_t)idx[q]*stride + src], s);
    cbpb[t] = s;
  }

  float l1 = soft[24+iter*4+1];
  float l2 = (iter>=1) ? soft[24+iter*4+2] : 0.f;
  float l3 = (iter>=2) ? soft[24+iter*4+3] : 0.f;
  float r1 = soft[36+iter*4+1];
  float r2 = (iter>=1) ? soft[36+iter*4+2] : 0.f;
  float r3 = (iter>=2) ? soft[36+iter*4+3] : 0.f;

  float acc[8][4];
  #pragma unroll
  for (int i = 0; i < 8; i++)
    #pragma unroll
    for (int j = 0; j < 4; j++) acc[i][j] = 0.f;

  // ---- phase A: proj = pw @ [lhs; rhs]
  for (int half = 0; half < 2; half++) {
    float cc1 = half ? r1 : l1, cc2 = half ? r2 : l2, cc3 = half ? r3 : l3;
    for (int k = t*4; k < 16384; k += 2048) {
      float4 v1 = *(const float4*)&h1[hb + k];
      float4 v;
      v.x = cc1*v1.x; v.y = cc1*v1.y; v.z = cc1*v1.z; v.w = cc1*v1.w;
      if (iter >= 1) {
        float4 v2 = *(const float4*)&h2[hb + k];
        v.x = fmaf(cc2, v2.x, v.x); v.y = fmaf(cc2, v2.y, v.y);
        v.z = fmaf(cc2, v2.z, v.z); v.w = fmaf(cc2, v2.w, v.w);
      }
      if (iter >= 2) {
        float4 v3 = *(const float4*)&h3[hb + k];
        v.x = fmaf(cc3, v3.x, v.x); v.y = fmaf(cc3, v3.y, v.y);
        v.z = fmaf(cc3, v3.z, v.z); v.w = fmaf(cc3, v3.w, v.w);
      }
      *(float4*)&inp[k] = v;
    }
    for (int k = t; k < 4096; k += 512) {
      int dl = k >> 6, o = k & 63;
      int src = o*128 + half*64 + dl;            // emb2 col of pw[o][d]
      float s = 0.f;
      #pragma unroll
      for (int q = 0; q < 8; q++) s = fmaf(a[q], emb2[(size_t)idx[q]*8256 + src], s);
      pwt[k] = s;
    }
    __syncthreads();
    for (int dl = 0; dl < 64; dl++) {
      float4 wA = *(const float4*)&pwt[dl*64 + o8];
      float4 wB = *(const float4*)&pwt[dl*64 + o8 + 4];
      float4 vA = *(const float4*)&inp[dl*256 + p4];
      float wv[8] = {wA.x,wA.y,wA.z,wA.w, wB.x,wB.y,wB.z,wB.w};
      float vv[4] = {vA.x,vA.y,vA.z,vA.w};
      #pragma unroll
      for (int oi = 0; oi < 8; oi++)
        #pragma unroll
        for (int pi = 0; pi < 4; pi++)
          acc[oi][pi] = fmaf(wv[oi], vv[pi], acc[oi][pi]);
    }
    __syncthreads();
  }

  // ---- write proj (+pb) into padded LDS
  float pbv[8];
  #pragma unroll
  for (int oi = 0; oi < 8; oi++) pbv[oi] = cbpb[64 + o8 + oi];
  for (int k = t; k < 23040; k += 512) ppad[k] = 0.f;
  __syncthreads();
  #pragma unroll
  for (int oi = 0; oi < 8; oi++)
    #pragma unroll
    for (int pi = 0; pi < 4; pi++)
      ppad[(o8+oi)*360 + (y+1)*20 + (x0+1) + pi] = acc[oi][pi] + pbv[oi];
  __syncthreads();

  // ---- phase B: per-sample conv 64->64, 3x3, pad1, + cb, relu
  float acc2[8][4];
  #pragma unroll
  for (int i = 0; i < 8; i++)
    #pragma unroll
    for (int j = 0; j < 4; j++) acc2[i][j] = 0.f;
  for (int icc = 0; icc < 8; icc++) {
    for (int k = t; k < 4608; k += 512) {
      int icl = k / 576; int rem = k - icl*576; int tap = rem >> 6; int oc = rem & 63;
      int src = oc*576 + (icc*8 + icl)*9 + tap;  // emb1 col of cw[oc][ic][tap]
      float s = 0.f;
      #pragma unroll
      for (int q = 0; q < 8; q++) s = fmaf(a[q], emb1[(size_t)idx[q]*36928 + src], s);
      cwt[k] = s;
    }
    __syncthreads();
    for (int icl = 0; icl < 8; icl++) {
      int ic = icc*8 + icl;
      float wn[3][6];
      #pragma unroll
      for (int r = 0; r < 3; r++) {
        const float* pr = &ppad[ic*360 + (y+r)*20 + x0];
        float4 aa = *(const float4*)&pr[0];
        float2 bb2 = *(const float2*)&pr[4];
        wn[r][0]=aa.x; wn[r][1]=aa.y; wn[r][2]=aa.z; wn[r][3]=aa.w;
        wn[r][4]=bb2.x; wn[r][5]=bb2.y;
      }
      #pragma unroll
      for (int dy = 0; dy < 3; dy++)
        #pragma unroll
        for (int dx = 0; dx < 3; dx++) {
          const float* cwp = &cwt[icl*576 + (dy*3+dx)*64 + o8];
          float4 wA = *(const float4*)&cwp[0];
          float4 wB = *(const float4*)&cwp[4];
          float wv[8] = {wA.x,wA.y,wA.z,wA.w, wB.x,wB.y,wB.z,wB.w};
          #pragma unroll
          for (int oi = 0; oi < 8; oi++)
            #pragma unroll
            for (int pi = 0; pi < 4; pi++)
              acc2[oi][pi] = fmaf(wv[oi], wn[dy][pi+dx], acc2[oi][pi]);
        }
    }
    __syncthreads();
  }
  float* ho = hout + hb;
  #pragma unroll
  for (int oi = 0; oi < 8; oi++) {
    float cb = cbpb[o8 + oi];
    float4 s0;
    float* p0 = (float*)&s0;
    #pragma unroll
    for (int pi = 0; pi < 4; pi++) p0[pi] = fmaxf(acc2[oi][pi] + cb, 0.f);
    *(float4*)&ho[(size_t)(o8+oi)*256 + y*16 + x0] = s0;
  }
}

// ---------------- K5: proj512 + relu + pool -> f (b, 32768) ----------------
// dynamic LDS 83968 B
__global__ __launch_bounds__(256) void k5_proj(
    const float* __restrict__ h4, const float* __restrict__ wproj,
    const float* __restrict__ bproj, float* __restrict__ f) {
  extern __shared__ float sm[];
  float* hbuf = sm;            // 16384 (reused as cbuf)
  float* wt   = sm + 16384;    // [64][72] = 4608
  int bx = blockIdx.x;         // 2048; XCD-aware remap
  int b = (bx & 7)*32 + ((bx >> 3) & 31);
  int ocb = (bx >> 8) * 64;
  int t = threadIdx.x;
  int og = t >> 5, pg = t & 31, o8 = og*8, p8 = pg*8;
  for (int k = t*4; k < 16384; k += 1024)
    *(float4*)&hbuf[k] = *(const float4*)&h4[(size_t)b*16384 + k];
  for (int k = t; k < 4096; k += 256) {
    int ol = k >> 6, c = k & 63;
    wt[c*72 + ol] = wproj[(size_t)(ocb+ol)*64 + c];
  }
  __syncthreads();
  float acc[8][8];
  #pragma unroll
  for (int i = 0; i < 8; i++)
    #pragma unroll
    for (int j = 0; j < 8; j++) acc[i][j] = 0.f;
  for (int d = 0; d < 64; d++) {
    float4 wA = *(const float4*)&wt[d*72 + o8];
    float4 wB = *(const float4*)&wt[d*72 + o8 + 4];
    float4 vA = *(const float4*)&hbuf[d*256 + p8];
    float4 vB = *(const float4*)&hbuf[d*256 + p8 + 4];
    float wv[8] = {wA.x,wA.y,wA.z,wA.w, wB.x,wB.y,wB.z,wB.w};
    float vv[8] = {vA.x,vA.y,vA.z,vA.w, vB.x,vB.y,vB.z,vB.w};
    #pragma unroll
    for (int oi = 0; oi < 8; oi++)
      #pragma unroll
      for (int pi = 0; pi < 8; pi++)
        acc[oi][pi] = fmaf(wv[oi], vv[pi], acc[oi][pi]);
  }
  __syncthreads();
  float bv[8];
  #pragma unroll
  for (int oi = 0; oi < 8; oi++) bv[oi] = bproj[ocb + o8 + oi];
  #pragma unroll
  for (int oi = 0; oi < 8; oi++)
    #pragma unroll
    for (int pi = 0; pi < 8; pi++)
      hbuf[(o8+oi)*256 + p8 + pi] = fmaxf(acc[oi][pi] + bv[oi], 0.f);
  __syncthreads();
  float* fb = f + (size_t)b*32768 + (size_t)ocb*64;
  for (int k = t; k < 4096; k += 256) {
    int oc = k >> 6, pp = k & 63, pyy = pp >> 3, pxx = pp & 7;
    const float* cb_ = &hbuf[oc*256 + pyy*32 + pxx*2];
    float m = fmaxf(fmaxf(cb_[0], cb_[1]), fmaxf(cb_[16], cb_[17]));
    fb[(size_t)oc*64 + pp] = m;
  }
}

// ---------------- K6a: fc1 partial GEMM (K-split 16), [k][m] LDS layout ------
__global__ __launch_bounds__(256) void k6_fc1(
    const float* __restrict__ f, const float* __restrict__ w,
    float* __restrict__ part) {
  __shared__ float ab[32*132];
  __shared__ float bb[32*132];
  int bx = blockIdx.x;   // 256 = (Ks*8 + Nt)*2 + Mt
  int Mb = (bx & 1)*128;
  int Nb = ((bx >> 1) & 7)*128;
  int Ks = bx >> 4;      // 0..15
  int t = threadIdx.x;
  int og = t >> 4, pg = t & 15, m8 = og*8, n8 = pg*8;
  int kr4 = (t & 7)*4, mr4 = t >> 3;
  float acc[8][8];
  #pragma unroll
  for (int i = 0; i < 8; i++)
    #pragma unroll
    for (int j = 0; j < 8; j++) acc[i][j] = 0.f;
  for (int kc = 0; kc < 64; kc++) {
    int k0 = Ks*2048 + kc*32;
    __syncthreads();
    #pragma unroll
    for (int pass = 0; pass < 4; pass++) {
      int m = pass*32 + mr4;
      float4 av = *(const float4*)&f[(size_t)(Mb+m)*32768 + k0 + kr4];
      float4 bv = *(const float4*)&w[(size_t)(Nb+m)*32768 + k0 + kr4];
      ab[(kr4+0)*132+m] = av.x; ab[(kr4+1)*132+m] = av.y;
      ab[(kr4+2)*132+m] = av.z; ab[(kr4+3)*132+m] = av.w;
      bb[(kr4+0)*132+m] = bv.x; bb[(kr4+1)*132+m] = bv.y;
      bb[(kr4+2)*132+m] = bv.z; bb[(kr4+3)*132+m] = bv.w;
    }
    __syncthreads();
    for (int k = 0; k < 32; k++) {
      float4 aA = *(const float4*)&ab[k*132 + m8];
      float4 aB = *(const float4*)&ab[k*132 + m8 + 4];
      float4 bA = *(const float4*)&bb[k*132 + n8];
      float4 bB = *(const float4*)&bb[k*132 + n8 + 4];
      float a8[8] = {aA.x,aA.y,aA.z,aA.w, aB.x,aB.y,aB.z,aB.w};
      float b8[8] = {bA.x,bA.y,bA.z,bA.w, bB.x,bB.y,bB.z,bB.w};
      #pragma unroll
      for (int mi = 0; mi < 8; mi++)
        #pragma unroll
        for (int ni = 0; ni < 8; ni++)
          acc[mi][ni] = fmaf(a8[mi], b8[ni], acc[mi][ni]);
    }
  }
  float* pb_ = part + (size_t)Ks*262144;
  #pragma unroll
  for (int mi = 0; mi < 8; mi++) {
    float4 s0, s1;
    float* p0 = (float*)&s0; float* p1 = (float*)&s1;
    #pragma unroll
    for (int ni = 0; ni < 4; ni++) p0[ni] = acc[mi][ni];
    #pragma unroll
    for (int ni = 0; ni < 4; ni++) p1[ni] = acc[mi][4+ni];
    *(float4*)&pb_[(size_t)(Mb+m8+mi)*1024 + Nb + n8]     = s0;
    *(float4*)&pb_[(size_t)(Mb+m8+mi)*1024 + Nb + n8 + 4] = s1;
  }
}

// ---------------- K6b: reduce partials + bias + relu ----------------
__global__ __launch_bounds__(256) void k6b_reduce(
    const float* __restrict__ part, const float* __restrict__ bias,
    float* __restrict__ f2) {
  int j = blockIdx.x*256 + threadIdx.x;   // < 262144
  float s = bias[j & 1023];
  #pragma unroll
  for (int ks = 0; ks < 16; ks++) s += part[(size_t)ks*262144 + j];
  f2[j] = fmaxf(s, 0.f);
}

// ---------------- K7: fc2 ----------------
__global__ __launch_bounds__(256) void k7_fc2(
    const float* __restrict__ f2, const float* __restrict__ w2,
    const float* __restrict__ b2, float* __restrict__ out) {
  __shared__ float r0[256], r1[256];
  int b = blockIdx.x, t = threadIdx.x;
  float s0 = 0.f, s1 = 0.f;
  #pragma unroll
  for (int q = 0; q < 4; q++) {
    int k = q*256 + t;
    float v = f2[(size_t)b*1024 + k];
    s0 = fmaf(v, w2[k], s0);
    s1 = fmaf(v, w2[1024+k], s1);
  }
  r0[t] = s0; r1[t] = s1; __syncthreads();
  for (int s = 128; s > 0; s >>= 1) {
    if (t < s) { r0[t] += r0[t+s]; r1[t] += r1[t+s]; }
    __syncthreads();
  }
  if (t == 0) { out[b*2] = r0[0] + b2[0]; out[b*2+1] = r1[0] + b2[1]; }
}

// ---------------- host ----------------
extern "C" void kernel_launch(void* const* d_in, const int* in_sizes, int n_in,
                              void* d_out, int out_size, void* d_ws, size_t ws_size,
                              hipStream_t stream) {
  const float* image  = (const float*)d_in[0];
  const int*   question = (const int*)d_in[1];
  const float* emb1   = (const float*)d_in[2];
  const float* emb2   = (const float*)d_in[3];
  const float* alpha  = (const float*)d_in[4];
  const float* tau0   = (const float*)d_in[5];
  const float* tau1   = (const float*)d_in[6];
  const float* w_s0   = (const float*)d_in[7];
  const float* b_s0   = (const float*)d_in[8];
  const float* w_s1   = (const float*)d_in[9];
  const float* b_s1   = (const float*)d_in[10];
  const float* w_proj = (const float*)d_in[11];
  const float* b_proj = (const float*)d_in[12];
  const float* w_fc1  = (const float*)d_in[13];
  const float* b_fc1  = (const float*)d_in[14];
  const float* w_fc2  = (const float*)d_in[15];
  const float* b_fc2  = (const float*)d_in[16];
  float* out = (float*)d_out;

  // ws layout (floats):
  //   [0,64)                     softmaxes
  //   [64, 64+36864)             w1t (transposed stem2 weights)
  //   [36928, 36928+16777216)    big region: x1 (stem1) -> f/part/f2
  //   [16814144, +16777216)      h buffers: h1..h4 (4 x 4194304)
  if (ws_size < (size_t)134365440) return;  // visible failure if ws too small
  float* ws   = (float*)d_ws;
  float* soft = ws;
  float* w1t  = ws + 64;
  float* big  = ws + 36928;
  float* x1   = big;
  float* f    = big;
  float* part = big + 8388608;
  float* f2   = big + 12582912;
  float* hbuf0 = ws + 36928 + 16777216;
  float* h[4] = { hbuf0, hbuf0 + 4194304, hbuf0 + 8388608, hbuf0 + 12582912 };

  hipFuncSetAttribute(reinterpret_cast<const void*>(k4_module),
                      hipFuncAttributeMaxDynamicSharedMemorySize, 110592);
  hipFuncSetAttribute(reinterpret_cast<const void*>(k5_proj),
                      hipFuncAttributeMaxDynamicSharedMemorySize, 83968);

  k0_softmax<<<1, 64, 0, stream>>>(alpha, tau0, tau1, soft);
  kpre_wt<<<144, 256, 0, stream>>>(w_s1, w1t);
  k1_stem1<<<512, 256, 0, stream>>>(image, w_s0, b_s0, x1);
  k2_stem2<<<1024, 256, 0, stream>>>(x1, w1t, b_s1, h[0]);
  for (int i = 0; i < 3; i++) {
    k4_module<<<256, 512, 110592, stream>>>(question, emb1, emb2, soft,
                                            h[0], h[1], h[2], h[i+1], i);
  }
  k5_proj<<<2048, 256, 83968, stream>>>(h[3], w_proj, b_proj, f);
  k6_fc1<<<256, 256, 0, stream>>>(f, w_fc1, part);
  k6b_reduce<<<1024, 256, 0, stream>>>(part, b_fc1, f2);
  k7_fc2<<<256, 256, 0, stream>>>(f2, w_fc2, b_fc2, out);
}

// Round 4
// 1372.651 us; speedup vs baseline: 1.6189x; 1.6189x over previous
//
#include <hip/hip_runtime.h>
#include <cstdint>

// ---------------- constants ----------------
// B=256, DIM=64, K=3, NQ=8, VOCAB=50
// E1 = 36928 (= 64 + 36864), E2 = 8256 (= 64 + 8192)
// qrep per sample (45184 floats), NATIVE emb order:
//   [0,36864):      cw[oc][ic][tap]   (emb1 cols)
//   [36864,36928):  cb[oc]            (emb1 cols)
//   [36928,45120):  pw[o][d]          (emb2 cols 0..8192)
//   [45120,45184):  pb[o]             (emb2 cols 8192..8256)

// ---------------- K0: softmaxes ----------------
__global__ void k0_softmax(const float* __restrict__ alpha,
                           const float* __restrict__ tau0,
                           const float* __restrict__ tau1,
                           float* __restrict__ soft) {
  int t = threadIdx.x;
  if (t < 3) {
    float m = -1e30f;
    for (int j = 0; j < 8; j++) m = fmaxf(m, alpha[t*8+j]);
    float e[8]; float s = 0.f;
    #pragma unroll
    for (int j = 0; j < 8; j++) { e[j] = expf(alpha[t*8+j]-m); s += e[j]; }
    #pragma unroll
    for (int j = 0; j < 8; j++) soft[t*8+j] = e[j]/s;
  } else if (t >= 4 && t < 7) {
    int i = t-4; int n = i+2;
    float m = -1e30f;
    for (int j = 0; j < n; j++) m = fmaxf(m, tau0[i*4+j]);
    float e[4]; float s = 0.f;
    for (int j = 0; j < n; j++) { e[j] = expf(tau0[i*4+j]-m); s += e[j]; }
    for (int j = 0; j < 4; j++) soft[24+i*4+j] = (j<n) ? e[j]/s : 0.f;
  } else if (t >= 8 && t < 11) {
    int i = t-8; int n = i+2;
    float m = -1e30f;
    for (int j = 0; j < n; j++) m = fmaxf(m, tau1[i*4+j]);
    float e[4]; float s = 0.f;
    for (int j = 0; j < n; j++) { e[j] = expf(tau1[i*4+j]-m); s += e[j]; }
    for (int j = 0; j < 4; j++) soft[36+i*4+j] = (j<n) ? e[j]/s : 0.f;
  }
}

// ---------------- Kpre: transpose w_s1 -> w1t[ic][tap][oc] ----------------
__global__ __launch_bounds__(256) void kpre_wt(const float* __restrict__ w1,
                                               float* __restrict__ w1t) {
  int i = blockIdx.x*256 + threadIdx.x;   // < 36864
  int oc = i / 576; int rem = i - oc*576; int ic = rem / 9; int tap = rem - ic*9;
  w1t[(ic*9 + tap)*64 + oc] = w1[i];
}

// ---------------- K1: stem conv1 (3->64, 64x64, pad1) + relu + pool -> (b,64,32,32)
__global__ __launch_bounds__(256) void k1_stem1(
    const float* __restrict__ image, const float* __restrict__ w0,
    const float* __restrict__ b0, float* __restrict__ x1) {
  __shared__ float img[3*66*66];   // padded planes
  __shared__ float wls[64*27];
  __shared__ float bls[64];
  int bx = blockIdx.x;             // 512 = b*2 + half
  int b = bx >> 1, half = bx & 1;
  int t = threadIdx.x;
  for (int i = t; i < 3*66*66; i += 256) img[i] = 0.f;
  for (int i = t; i < 1728; i += 256) wls[i] = w0[i];
  if (t < 64) bls[t] = b0[t];
  __syncthreads();
  const float* ib = image + (size_t)b*3*4096;
  for (int i = t*4; i < 12288; i += 1024) {
    float4 v = *(const float4*)&ib[i];
    int c = i >> 12, r = (i >> 6) & 63, x = i & 63;
    float* dst = &img[c*4356 + (r+1)*66 + (x+1)];
    dst[0]=v.x; dst[1]=v.y; dst[2]=v.z; dst[3]=v.w;
  }
  __syncthreads();
  int py = t >> 3, px0 = (t & 7) * 4;
  float* outb = x1 + ((size_t)b*64 + half*32)*1024;
  for (int oc = 0; oc < 32; oc++) {
    int oco = half*32 + oc;
    float val[2][8];
    #pragma unroll
    for (int r = 0; r < 2; r++)
      #pragma unroll
      for (int c = 0; c < 8; c++) val[r][c] = 0.f;
    #pragma unroll
    for (int ic = 0; ic < 3; ic++) {
      float wn[4][10];
      #pragma unroll
      for (int r = 0; r < 4; r++) {
        #pragma unroll
        for (int c = 0; c < 10; c += 2) {
          float2 v = *(const float2*)&img[ic*4356 + (2*py+r)*66 + 2*px0 + c];
          wn[r][c] = v.x; wn[r][c+1] = v.y;
        }
      }
      const float* wp = &wls[oco*27 + ic*9];
      float w9[9];
      #pragma unroll
      for (int j = 0; j < 9; j++) w9[j] = wp[j];
      #pragma unroll
      for (int dy = 0; dy < 3; dy++)
        #pragma unroll
        for (int dx = 0; dx < 3; dx++) {
          float w = w9[dy*3+dx];
          #pragma unroll
          for (int r = 0; r < 2; r++)
            #pragma unroll
            for (int c = 0; c < 8; c++)
              val[r][c] = fmaf(w, wn[r+dy][c+dx], val[r][c]);
        }
    }
    float bias = bls[oco];
    float4 o4;
    float* po = (float*)&o4;
    #pragma unroll
    for (int c = 0; c < 4; c++) {
      float m = fmaxf(fmaxf(val[0][2*c], val[0][2*c+1]),
                      fmaxf(val[1][2*c], val[1][2*c+1]));
      po[c] = fmaxf(m + bias, 0.f);
    }
    *(float4*)&outb[(size_t)oc*1024 + py*32 + px0] = o4;
  }
}

// ---------------- K2: stem conv2 (64->64, 32x32, pad1) + relu + pool -> h1 (b,64,16,16)
__global__ __launch_bounds__(256) void k2_stem2(
    const float* __restrict__ x1, const float* __restrict__ w1t,
    const float* __restrict__ b1, float* __restrict__ h1) {
  __shared__ float inp[8*34*34];   // 9248 floats, padded planes (chunk of 8 in-ch)
  int bx = blockIdx.x;
  int b  = (bx & 7)*32 + ((bx >> 3) & 31);
  int ocb = (bx >> 8) * 16;        // 4 groups of 16 out-channels
  int t = threadIdx.x;
  for (int i = t; i < 9248; i += 256) inp[i] = 0.f;
  int py = t >> 4, px = t & 15;
  float val[16][2][2];
  #pragma unroll
  for (int o = 0; o < 16; o++) { val[o][0][0]=0.f; val[o][0][1]=0.f; val[o][1][0]=0.f; val[o][1][1]=0.f; }
  const float* xb = x1 + (size_t)b*65536;
  for (int icc = 0; icc < 8; icc++) {
    __syncthreads();
    for (int i = t*4; i < 8192; i += 1024) {
      int icl = i >> 10;
      float4 v = *(const float4*)&xb[(size_t)(icc*8+icl)*1024 + (i & 1023)];
      float* dst = &inp[icl*1156 + (((i>>5)&31)+1)*34 + (i&31) + 1];
      dst[0]=v.x; dst[1]=v.y; dst[2]=v.z; dst[3]=v.w;
    }
    __syncthreads();
    for (int icl = 0; icl < 8; icl++) {
      int ic = icc*8 + icl;
      float wn[4][4];
      #pragma unroll
      for (int r = 0; r < 4; r++) {
        float2 v0 = *(const float2*)&inp[icl*1156 + (2*py+r)*34 + 2*px];
        float2 v1 = *(const float2*)&inp[icl*1156 + (2*py+r)*34 + 2*px + 2];
        wn[r][0]=v0.x; wn[r][1]=v0.y; wn[r][2]=v1.x; wn[r][3]=v1.y;
      }
      const float* wrow = w1t + (size_t)ic*576 + ocb;   // uniform address
      #pragma unroll
      for (int tap = 0; tap < 9; tap++) {
        const float4* wp = (const float4*)(wrow + tap*64);
        float4 wv0 = wp[0], wv1 = wp[1], wv2 = wp[2], wv3 = wp[3];
        float w16[16] = {wv0.x,wv0.y,wv0.z,wv0.w, wv1.x,wv1.y,wv1.z,wv1.w,
                         wv2.x,wv2.y,wv2.z,wv2.w, wv3.x,wv3.y,wv3.z,wv3.w};
        int dy = tap / 3, dx = tap - dy*3;
        #pragma unroll
        for (int oc = 0; oc < 16; oc++) {
          float w = w16[oc];
          #pragma unroll
          for (int r = 0; r < 2; r++)
            #pragma unroll
            for (int c = 0; c < 2; c++)
              val[oc][r][c] = fmaf(w, wn[r+dy][c+dx], val[oc][r][c]);
        }
      }
    }
  }
  float* hb = h1 + ((size_t)b*64 + ocb)*256;
  #pragma unroll
  for (int oc = 0; oc < 16; oc++) {
    float m = fmaxf(fmaxf(val[oc][0][0], val[oc][0][1]),
                    fmaxf(val[oc][1][0], val[oc][1][1]));
    hb[(size_t)oc*256 + py*16 + px] = fmaxf(m + b1[ocb+oc], 0.f);
  }
}

// ---------------- K3: blend qrep in native emb order (coalesced both sides) ----
__global__ __launch_bounds__(256) void k3_blend(
    const int* __restrict__ question, const float* __restrict__ emb1,
    const float* __restrict__ emb2, const float* __restrict__ soft,
    float* __restrict__ qrep, int iter) {
  int b = blockIdx.y;
  int part = blockIdx.x;          // 0..11, each covers 944 float4s
  int t = threadIdx.x;
  int idx[8]; float a[8];
  #pragma unroll
  for (int q = 0; q < 8; q++) { idx[q] = question[b*8+q]; a[q] = soft[iter*8+q]; }
  float* qb = qrep + (size_t)b*45184;
  #pragma unroll
  for (int i = 0; i < 4; i++) {
    int r = i*256 + t;
    int j4 = part*944 + r;
    if (r < 944 && j4 < 11296) {
      int j = j4*4;
      float4 acc = {0.f,0.f,0.f,0.f};
      if (j < 36928) {
        #pragma unroll
        for (int q = 0; q < 8; q++) {
          float4 v = *(const float4*)&emb1[(size_t)idx[q]*36928 + j];
          acc.x = fmaf(a[q], v.x, acc.x); acc.y = fmaf(a[q], v.y, acc.y);
          acc.z = fmaf(a[q], v.z, acc.z); acc.w = fmaf(a[q], v.w, acc.w);
        }
      } else {
        int jj = j - 36928;
        #pragma unroll
        for (int q = 0; q < 8; q++) {
          float4 v = *(const float4*)&emb2[(size_t)idx[q]*8256 + jj];
          acc.x = fmaf(a[q], v.x, acc.x); acc.y = fmaf(a[q], v.y, acc.y);
          acc.z = fmaf(a[q], v.z, acc.z); acc.w = fmaf(a[q], v.w, acc.w);
        }
      }
      *(float4*)&qb[j] = acc;
    }
  }
}

// ---------------- K4: fused module (blend -> proj -> per-sample conv) ----------
// one block per sample, 512 threads; dynamic LDS 141312 B; reads materialized qrep.
// Double-buffered staging: global->reg issued before compute, reg->LDS after barrier.
__global__ __launch_bounds__(512) void k4_module(
    const float* __restrict__ qrep, const float* __restrict__ soft,
    const float* __restrict__ h1, const float* __restrict__ h2,
    const float* __restrict__ h3, float* __restrict__ hout, int iter) {
  extern __shared__ float sm[];
  // phase A (words 0..20479): inp dbuf 2x8192 @0, pws dbuf 2x2048 @16384
  // phase B (words 0..35327): ppad 23040 @0, cwt dbuf 2x6144 @23040/@29184
  float* inpB0 = sm;
  float* inpB1 = sm + 8192;
  float* pwsB0 = sm + 16384;
  float* pwsB1 = sm + 18432;
  float* ppad  = sm;
  float* cwtB0 = sm + 23040;
  float* cwtB1 = sm + 29184;
  __shared__ float cbpb[128];  // cb[64] | pb[64]
  int b = blockIdx.x;
  int t = threadIdx.x;
  int og = t >> 6, pg = t & 63;
  int o8 = og*8, p4 = pg*4;
  int y = pg >> 2, x0 = (pg & 3)*4;
  size_t hb = (size_t)b*16384;
  const float* qb = qrep + (size_t)b*45184;

  if (t < 64) cbpb[t] = qb[36864 + t];
  else if (t < 128) cbpb[t] = qb[45120 + (t - 64)];

  float l1 = soft[24+iter*4+1];
  float l2 = (iter>=1) ? soft[24+iter*4+2] : 0.f;
  float l3 = (iter>=2) ? soft[24+iter*4+3] : 0.f;
  float r1 = soft[36+iter*4+1];
  float r2 = (iter>=1) ? soft[36+iter*4+2] : 0.f;
  float r3 = (iter>=2) ? soft[36+iter*4+3] : 0.f;

  // ---------- phase A: proj = pw @ [lhs; rhs], 4 chunks of 32 input-dims ----------
  float acc[8][4];
  #pragma unroll
  for (int i = 0; i < 8; i++)
    #pragma unroll
    for (int j = 0; j < 4; j++) acc[i][j] = 0.f;

  auto issueA = [&](int c, float4* v1, float4* v2, float4* v3, float4& pw) {
    #pragma unroll
    for (int p = 0; p < 4; p++) {
      int i4 = t + p*512;                 // 0..2047
      int dl = i4 >> 6;                   // 0..31
      int pix = (i4 & 63) * 4;
      int ch = (c & 1)*32 + dl;           // channel within h (d & 63)
      size_t off = hb + (size_t)ch*256 + pix;
      v1[p] = *(const float4*)&h1[off];
      if (iter >= 1) v2[p] = *(const float4*)&h2[off];
      if (iter >= 2) v3[p] = *(const float4*)&h3[off];
    }
    int o = t >> 3, dq = (t & 7)*4;
    pw = *(const float4*)&qb[36928 + o*128 + c*32 + dq];
  };
  auto writeA = [&](int c, float4* v1, float4* v2, float4* v3, float4& pw,
                    float* inpb, float* pwsb) {
    float c1 = (c >= 2) ? r1 : l1;
    float c2 = (c >= 2) ? r2 : l2;
    float c3 = (c >= 2) ? r3 : l3;
    #pragma unroll
    for (int p = 0; p < 4; p++) {
      int i4 = t + p*512;
      int dl = i4 >> 6;
      int pix = (i4 & 63) * 4;
      float4 v;
      v.x = c1*v1[p].x; v.y = c1*v1[p].y; v.z = c1*v1[p].z; v.w = c1*v1[p].w;
      if (iter >= 1) {
        v.x = fmaf(c2, v2[p].x, v.x); v.y = fmaf(c2, v2[p].y, v.y);
        v.z = fmaf(c2, v2[p].z, v.z); v.w = fmaf(c2, v2[p].w, v.w);
      }
      if (iter >= 2) {
        v.x = fmaf(c3, v3[p].x, v.x); v.y = fmaf(c3, v3[p].y, v.y);
        v.z = fmaf(c3, v3[p].z, v.z); v.w = fmaf(c3, v3[p].w, v.w);
      }
      *(float4*)&inpb[dl*256 + pix] = v;
    }
    int o = t >> 3, dq = (t & 7)*4;
    *(float4*)&pwsb[o*32 + dq] = pw;
  };

  {
    float4 a1[4], a2[4], a3[4], apw;
    issueA(0, a1, a2, a3, apw);
    writeA(0, a1, a2, a3, apw, inpB0, pwsB0);
  }
  __syncthreads();
  #pragma unroll
  for (int c = 0; c < 4; c++) {
    float4 b1v[4], b2v[4], b3v[4], bpw;
    if (c < 3) issueA(c+1, b1v, b2v, b3v, bpw);
    float* inpb = (c & 1) ? inpB1 : inpB0;
    float* pwsb = (c & 1) ? pwsB1 : pwsB0;
    for (int dl = 0; dl < 32; dl++) {
      float w[8];
      #pragma unroll
      for (int oi = 0; oi < 8; oi++) w[oi] = pwsb[(o8+oi)*32 + dl];
      float4 v = *(const float4*)&inpb[dl*256 + p4];
      float vv[4] = {v.x, v.y, v.z, v.w};
      #pragma unroll
      for (int oi = 0; oi < 8; oi++)
        #pragma unroll
        for (int pi = 0; pi < 4; pi++)
          acc[oi][pi] = fmaf(w[oi], vv[pi], acc[oi][pi]);
    }
    __syncthreads();
    if (c < 3) {
      writeA(c+1, b1v, b2v, b3v, bpw, (c & 1) ? inpB0 : inpB1,
             (c & 1) ? pwsB0 : pwsB1);
      __syncthreads();
    }
  }

  // ---------- proj (+pb) into padded LDS ----------
  float pbv[8];
  #pragma unroll
  for (int oi = 0; oi < 8; oi++) pbv[oi] = cbpb[64 + o8 + oi];
  for (int k = t; k < 23040; k += 512) ppad[k] = 0.f;
  __syncthreads();
  #pragma unroll
  for (int oi = 0; oi < 8; oi++)
    #pragma unroll
    for (int pi = 0; pi < 4; pi++)
      ppad[(o8+oi)*360 + (y+1)*20 + (x0+1) + pi] = acc[oi][pi] + pbv[oi];
  __syncthreads();

  // ---------- phase B: per-sample conv 64->64, 3x3, pad1, + cb, relu ----------
  float acc2[8][4];
  #pragma unroll
  for (int i = 0; i < 8; i++)
    #pragma unroll
    for (int j = 0; j < 4; j++) acc2[i][j] = 0.f;

  auto issueB = [&](int icc, float* r) {
    #pragma unroll
    for (int p = 0; p < 9; p++) {
      int i = t + p*512;               // 0..4607
      int oc = i / 72;
      int jj = i - oc*72;
      r[p] = qb[oc*576 + icc*72 + jj];
    }
  };
  auto writeB = [&](float* r, float* cwtb) {
    #pragma unroll
    for (int p = 0; p < 9; p++) {
      int i = t + p*512;
      int oc = i / 72;
      int jj = i - oc*72;
      int icl = jj / 9;
      int tap = jj - icl*9;
      cwtb[oc*96 + icl*12 + tap] = r[p];
    }
  };

  {
    float rg[9];
    issueB(0, rg);
    writeB(rg, cwtB0);
  }
  __syncthreads();
  #pragma unroll 1
  for (int icc = 0; icc < 8; icc++) {
    float rn[9];
    if (icc < 7) issueB(icc+1, rn);
    float* cwtb = (icc & 1) ? cwtB1 : cwtB0;
    for (int icl = 0; icl < 8; icl++) {
      int ic = icc*8 + icl;
      float wn[3][6];
      #pragma unroll
      for (int r = 0; r < 3; r++) {
        const float* pr = &ppad[ic*360 + (y+r)*20 + x0];
        float4 aa = *(const float4*)&pr[0];
        float2 bb2 = *(const float2*)&pr[4];
        wn[r][0]=aa.x; wn[r][1]=aa.y; wn[r][2]=aa.z; wn[r][3]=aa.w;
        wn[r][4]=bb2.x; wn[r][5]=bb2.y;
      }
      #pragma unroll
      for (int oi = 0; oi < 8; oi++) {
        const float* wp = &cwtb[(o8+oi)*96 + icl*12];
        float4 wA = *(const float4*)&wp[0];
        float4 wB = *(const float4*)&wp[4];
        float w8v = wp[8];
        float w9[9] = {wA.x,wA.y,wA.z,wA.w, wB.x,wB.y,wB.z,wB.w, w8v};
        #pragma unroll
        for (int dy = 0; dy < 3; dy++)
          #pragma unroll
          for (int dx = 0; dx < 3; dx++) {
            float w = w9[dy*3+dx];
            #pragma unroll
            for (int pi = 0; pi < 4; pi++)
              acc2[oi][pi] = fmaf(w, wn[dy][pi+dx], acc2[oi][pi]);
          }
      }
    }
    __syncthreads();
    if (icc < 7) {
      writeB(rn, (icc & 1) ? cwtB0 : cwtB1);
      __syncthreads();
    }
  }

  float* ho = hout + hb;
  #pragma unroll
  for (int oi = 0; oi < 8; oi++) {
    float cb = cbpb[o8 + oi];
    float4 s0;
    float* p0 = (float*)&s0;
    #pragma unroll
    for (int pi = 0; pi < 4; pi++) p0[pi] = fmaxf(acc2[oi][pi] + cb, 0.f);
    *(float4*)&ho[(size_t)(o8+oi)*256 + y*16 + x0] = s0;
  }
}

// ---------------- K5: proj512 + relu + pool -> f (b, 32768) ----------------
// dynamic LDS 83968 B
__global__ __launch_bounds__(256) void k5_proj(
    const float* __restrict__ h4, const float* __restrict__ wproj,
    const float* __restrict__ bproj, float* __restrict__ f) {
  extern __shared__ float sm[];
  float* hbuf = sm;            // 16384 (reused as cbuf)
  float* wt   = sm + 16384;    // [64][72] = 4608
  int bx = blockIdx.x;         // 2048; XCD-aware remap
  int b = (bx & 7)*32 + ((bx >> 3) & 31);
  int ocb = (bx >> 8) * 64;
  int t = threadIdx.x;
  int og = t >> 5, pg = t & 31, o8 = og*8, p8 = pg*8;
  for (int k = t*4; k < 16384; k += 1024)
    *(float4*)&hbuf[k] = *(const float4*)&h4[(size_t)b*16384 + k];
  for (int k = t; k < 4096; k += 256) {
    int ol = k >> 6, c = k & 63;
    wt[c*72 + ol] = wproj[(size_t)(ocb+ol)*64 + c];
  }
  __syncthreads();
  float acc[8][8];
  #pragma unroll
  for (int i = 0; i < 8; i++)
    #pragma unroll
    for (int j = 0; j < 8; j++) acc[i][j] = 0.f;
  for (int d = 0; d < 64; d++) {
    float4 wA = *(const float4*)&wt[d*72 + o8];
    float4 wB = *(const float4*)&wt[d*72 + o8 + 4];
    float4 vA = *(const float4*)&hbuf[d*256 + p8];
    float4 vB = *(const float4*)&hbuf[d*256 + p8 + 4];
    float wv[8] = {wA.x,wA.y,wA.z,wA.w, wB.x,wB.y,wB.z,wB.w};
    float vv[8] = {vA.x,vA.y,vA.z,vA.w, vB.x,vB.y,vB.z,vB.w};
    #pragma unroll
    for (int oi = 0; oi < 8; oi++)
      #pragma unroll
      for (int pi = 0; pi < 8; pi++)
        acc[oi][pi] = fmaf(wv[oi], vv[pi], acc[oi][pi]);
  }
  __syncthreads();
  float bv[8];
  #pragma unroll
  for (int oi = 0; oi < 8; oi++) bv[oi] = bproj[ocb + o8 + oi];
  #pragma unroll
  for (int oi = 0; oi < 8; oi++)
    #pragma unroll
    for (int pi = 0; pi < 8; pi++)
      hbuf[(o8+oi)*256 + p8 + pi] = fmaxf(acc[oi][pi] + bv[oi], 0.f);
  __syncthreads();
  float* fb = f + (size_t)b*32768 + (size_t)ocb*64;
  for (int k = t; k < 4096; k += 256) {
    int oc = k >> 6, pp = k & 63, pyy = pp >> 3, pxx = pp & 7;
    const float* cb_ = &hbuf[oc*256 + pyy*32 + pxx*2];
    float m = fmaxf(fmaxf(cb_[0], cb_[1]), fmaxf(cb_[16], cb_[17]));
    fb[(size_t)oc*64 + pp] = m;
  }
}

// ---------------- K6a: fc1 partial GEMM (K-split 16), [k][m] LDS layout ------
__global__ __launch_bounds__(256) void k6_fc1(
    const float* __restrict__ f, const float* __restrict__ w,
    float* __restrict__ part) {
  __shared__ float ab[32*132];
  __shared__ float bb[32*132];
  int bx = blockIdx.x;   // 256 = (Ks*8 + Nt)*2 + Mt
  int Mb = (bx & 1)*128;
  int Nb = ((bx >> 1) & 7)*128;
  int Ks = bx >> 4;      // 0..15
  int t = threadIdx.x;
  int og = t >> 4, pg = t & 15, m8 = og*8, n8 = pg*8;
  int kr4 = (t & 7)*4, mr4 = t >> 3;
  float acc[8][8];
  #pragma unroll
  for (int i = 0; i < 8; i++)
    #pragma unroll
    for (int j = 0; j < 8; j++) acc[i][j] = 0.f;
  for (int kc = 0; kc < 64; kc++) {
    int k0 = Ks*2048 + kc*32;
    __syncthreads();
    #pragma unroll
    for (int pass = 0; pass < 4; pass++) {
      int m = pass*32 + mr4;
      float4 av = *(const float4*)&f[(size_t)(Mb+m)*32768 + k0 + kr4];
      float4 bv = *(const float4*)&w[(size_t)(Nb+m)*32768 + k0 + kr4];
      ab[(kr4+0)*132+m] = av.x; ab[(kr4+1)*132+m] = av.y;
      ab[(kr4+2)*132+m] = av.z; ab[(kr4+3)*132+m] = av.w;
      bb[(kr4+0)*132+m] = bv.x; bb[(kr4+1)*132+m] = bv.y;
      bb[(kr4+2)*132+m] = bv.z; bb[(kr4+3)*132+m] = bv.w;
    }
    __syncthreads();
    for (int k = 0; k < 32; k++) {
      float4 aA = *(const float4*)&ab[k*132 + m8];
      float4 aB = *(const float4*)&ab[k*132 + m8 + 4];
      float4 bA = *(const float4*)&bb[k*132 + n8];
      float4 bB = *(const float4*)&bb[k*132 + n8 + 4];
      float a8[8] = {aA.x,aA.y,aA.z,aA.w, aB.x,aB.y,aB.z,aB.w};
      float b8[8] = {bA.x,bA.y,bA.z,bA.w, bB.x,bB.y,bB.z,bB.w};
      #pragma unroll
      for (int mi = 0; mi < 8; mi++)
        #pragma unroll
        for (int ni = 0; ni < 8; ni++)
          acc[mi][ni] = fmaf(a8[mi], b8[ni], acc[mi][ni]);
    }
  }
  float* pb_ = part + (size_t)Ks*262144;
  #pragma unroll
  for (int mi = 0; mi < 8; mi++) {
    float4 s0, s1;
    float* p0 = (float*)&s0; float* p1 = (float*)&s1;
    #pragma unroll
    for (int ni = 0; ni < 4; ni++) p0[ni] = acc[mi][ni];
    #pragma unroll
    for (int ni = 0; ni < 4; ni++) p1[ni] = acc[mi][4+ni];
    *(float4*)&pb_[(size_t)(Mb+m8+mi)*1024 + Nb + n8]     = s0;
    *(float4*)&pb_[(size_t)(Mb+m8+mi)*1024 + Nb + n8 + 4] = s1;
  }
}

// ---------------- K6b: reduce partials + bias + relu ----------------
__global__ __launch_bounds__(256) void k6b_reduce(
    const float* __restrict__ part, const float* __restrict__ bias,
    float* __restrict__ f2) {
  int j = blockIdx.x*256 + threadIdx.x;   // < 262144
  float s = bias[j & 1023];
  #pragma unroll
  for (int ks = 0; ks < 16; ks++) s += part[(size_t)ks*262144 + j];
  f2[j] = fmaxf(s, 0.f);
}

// ---------------- K7: fc2 ----------------
__global__ __launch_bounds__(256) void k7_fc2(
    const float* __restrict__ f2, const float* __restrict__ w2,
    const float* __restrict__ b2, float* __restrict__ out) {
  __shared__ float r0[256], r1[256];
  int b = blockIdx.x, t = threadIdx.x;
  float s0 = 0.f, s1 = 0.f;
  #pragma unroll
  for (int q = 0; q < 4; q++) {
    int k = q*256 + t;
    float v = f2[(size_t)b*1024 + k];
    s0 = fmaf(v, w2[k], s0);
    s1 = fmaf(v, w2[1024+k], s1);
  }
  r0[t] = s0; r1[t] = s1; __syncthreads();
  for (int s = 128; s > 0; s >>= 1) {
    if (t < s) { r0[t] += r0[t+s]; r1[t] += r1[t+s]; }
    __syncthreads();
  }
  if (t == 0) { out[b*2] = r0[0] + b2[0]; out[b*2+1] = r1[0] + b2[1]; }
}

// ---------------- host ----------------
extern "C" void kernel_launch(void* const* d_in, const int* in_sizes, int n_in,
                              void* d_out, int out_size, void* d_ws, size_t ws_size,
                              hipStream_t stream) {
  const float* image  = (const float*)d_in[0];
  const int*   question = (const int*)d_in[1];
  const float* emb1   = (const float*)d_in[2];
  const float* emb2   = (const float*)d_in[3];
  const float* alpha  = (const float*)d_in[4];
  const float* tau0   = (const float*)d_in[5];
  const float* tau1   = (const float*)d_in[6];
  const float* w_s0   = (const float*)d_in[7];
  const float* b_s0   = (const float*)d_in[8];
  const float* w_s1   = (const float*)d_in[9];
  const float* b_s1   = (const float*)d_in[10];
  const float* w_proj = (const float*)d_in[11];
  const float* b_proj = (const float*)d_in[12];
  const float* w_fc1  = (const float*)d_in[13];
  const float* b_fc1  = (const float*)d_in[14];
  const float* w_fc2  = (const float*)d_in[15];
  const float* b_fc2  = (const float*)d_in[16];
  float* out = (float*)d_out;

  // ws layout (floats):
  //   [0,64)                  softmaxes
  //   [64, 64+36864)          w1t
  //   big @36928 (16777216):  x1 (16.7M) -> qrep (11.57M) -> f(8.39M)+part(4.19M)+f2(0.26M)
  //   h  @36928+16777216:     h1..h4 (4 x 4194304)
  if (ws_size < (size_t)134365440) return;  // visible failure if ws too small
  float* ws   = (float*)d_ws;
  float* soft = ws;
  float* w1t  = ws + 64;
  float* big  = ws + 36928;
  float* x1   = big;
  float* qrep = big;
  float* f    = big;
  float* part = big + 8388608;
  float* f2   = big + 12582912;
  float* hbuf0 = ws + 36928 + 16777216;
  float* h[4] = { hbuf0, hbuf0 + 4194304, hbuf0 + 8388608, hbuf0 + 12582912 };

  hipFuncSetAttribute(reinterpret_cast<const void*>(k4_module),
                      hipFuncAttributeMaxDynamicSharedMemorySize, 141312);
  hipFuncSetAttribute(reinterpret_cast<const void*>(k5_proj),
                      hipFuncAttributeMaxDynamicSharedMemorySize, 83968);

  k0_softmax<<<1, 64, 0, stream>>>(alpha, tau0, tau1, soft);
  kpre_wt<<<144, 256, 0, stream>>>(w_s1, w1t);
  k1_stem1<<<512, 256, 0, stream>>>(image, w_s0, b_s0, x1);
  k2_stem2<<<1024, 256, 0, stream>>>(x1, w1t, b_s1, h[0]);
  for (int i = 0; i < 3; i++) {
    k3_blend<<<dim3(12, 256), 256, 0, stream>>>(question, emb1, emb2, soft, qrep, i);
    k4_module<<<256, 512, 141312, stream>>>(qrep, soft, h[0], h[1], h[2], h[i+1], i);
  }
  k5_proj<<<2048, 256, 83968, stream>>>(h[3], w_proj, b_proj, f);
  k6_fc1<<<256, 256, 0, stream>>>(f, w_fc1, part);
  k6b_reduce<<<1024, 256, 0, stream>>>(part, b_fc1, f2);
  k7_fc2<<<256, 256, 0, stream>>>(f2, w_fc2, b_fc2, out);
}

// Round 8
// 1230.089 us; speedup vs baseline: 1.8065x; 1.1159x over previous
//
#include <hip/hip_runtime.h>
#include <cstdint>

// ---------------- constants ----------------
// B=256, DIM=64, K=3, NQ=8, VOCAB=50
// E1 = 36928 (= 64 + 36864), E2 = 8256 (= 64 + 8192)
// qrep per sample (45184 floats), NATIVE emb order:
//   [0,36864):      cw[oc][ic][tap]   (emb1 cols)
//   [36864,36928):  cb[oc]            (emb1 cols)
//   [36928,45120):  pw[o][d]          (emb2 cols 0..8192)
//   [45120,45184):  pb[o]             (emb2 cols 8192..8256)

// ---------------- K0: softmaxes ----------------
__global__ void k0_softmax(const float* __restrict__ alpha,
                           const float* __restrict__ tau0,
                           const float* __restrict__ tau1,
                           float* __restrict__ soft) {
  int t = threadIdx.x;
  if (t < 3) {
    float m = -1e30f;
    for (int j = 0; j < 8; j++) m = fmaxf(m, alpha[t*8+j]);
    float e[8]; float s = 0.f;
    #pragma unroll
    for (int j = 0; j < 8; j++) { e[j] = expf(alpha[t*8+j]-m); s += e[j]; }
    #pragma unroll
    for (int j = 0; j < 8; j++) soft[t*8+j] = e[j]/s;
  } else if (t >= 4 && t < 7) {
    int i = t-4; int n = i+2;
    float m = -1e30f;
    for (int j = 0; j < n; j++) m = fmaxf(m, tau0[i*4+j]);
    float e[4]; float s = 0.f;
    for (int j = 0; j < n; j++) { e[j] = expf(tau0[i*4+j]-m); s += e[j]; }
    for (int j = 0; j < 4; j++) soft[24+i*4+j] = (j<n) ? e[j]/s : 0.f;
  } else if (t >= 8 && t < 11) {
    int i = t-8; int n = i+2;
    float m = -1e30f;
    for (int j = 0; j < n; j++) m = fmaxf(m, tau1[i*4+j]);
    float e[4]; float s = 0.f;
    for (int j = 0; j < n; j++) { e[j] = expf(tau1[i*4+j]-m); s += e[j]; }
    for (int j = 0; j < 4; j++) soft[36+i*4+j] = (j<n) ? e[j]/s : 0.f;
  }
}

// ---------------- Kpre: transpose w_s1 -> w1t[ic][tap][oc] ----------------
__global__ __launch_bounds__(256) void kpre_wt(const float* __restrict__ w1,
                                               float* __restrict__ w1t) {
  int i = blockIdx.x*256 + threadIdx.x;   // < 36864
  int oc = i / 576; int rem = i - oc*576; int ic = rem / 9; int tap = rem - ic*9;
  w1t[(ic*9 + tap)*64 + oc] = w1[i];
}

// ---------------- K1: stem conv1 (3->64, 64x64, pad1) + relu + pool -> (b,64,32,32)
__global__ __launch_bounds__(256) void k1_stem1(
    const float* __restrict__ image, const float* __restrict__ w0,
    const float* __restrict__ b0, float* __restrict__ x1) {
  __shared__ float img[3*66*66];   // padded planes
  __shared__ float wls[64*27];
  __shared__ float bls[64];
  int bx = blockIdx.x;             // 512 = b*2 + half
  int b = bx >> 1, half = bx & 1;
  int t = threadIdx.x;
  for (int i = t; i < 3*66*66; i += 256) img[i] = 0.f;
  for (int i = t; i < 1728; i += 256) wls[i] = w0[i];
  if (t < 64) bls[t] = b0[t];
  __syncthreads();
  const float* ib = image + (size_t)b*3*4096;
  for (int i = t*4; i < 12288; i += 1024) {
    float4 v = *(const float4*)&ib[i];
    int c = i >> 12, r = (i >> 6) & 63, x = i & 63;
    float* dst = &img[c*4356 + (r+1)*66 + (x+1)];
    dst[0]=v.x; dst[1]=v.y; dst[2]=v.z; dst[3]=v.w;
  }
  __syncthreads();
  int py = t >> 3, px0 = (t & 7) * 4;
  float* outb = x1 + ((size_t)b*64 + half*32)*1024;
  for (int oc = 0; oc < 32; oc++) {
    int oco = half*32 + oc;
    float val[2][8];
    #pragma unroll
    for (int r = 0; r < 2; r++)
      #pragma unroll
      for (int c = 0; c < 8; c++) val[r][c] = 0.f;
    #pragma unroll
    for (int ic = 0; ic < 3; ic++) {
      float wn[4][10];
      #pragma unroll
      for (int r = 0; r < 4; r++) {
        #pragma unroll
        for (int c = 0; c < 10; c += 2) {
          float2 v = *(const float2*)&img[ic*4356 + (2*py+r)*66 + 2*px0 + c];
          wn[r][c] = v.x; wn[r][c+1] = v.y;
        }
      }
      const float* wp = &wls[oco*27 + ic*9];
      float w9[9];
      #pragma unroll
      for (int j = 0; j < 9; j++) w9[j] = wp[j];
      #pragma unroll
      for (int dy = 0; dy < 3; dy++)
        #pragma unroll
        for (int dx = 0; dx < 3; dx++) {
          float w = w9[dy*3+dx];
          #pragma unroll
          for (int r = 0; r < 2; r++)
            #pragma unroll
            for (int c = 0; c < 8; c++)
              val[r][c] = fmaf(w, wn[r+dy][c+dx], val[r][c]);
        }
    }
    float bias = bls[oco];
    float4 o4;
    float* po = (float*)&o4;
    #pragma unroll
    for (int c = 0; c < 4; c++) {
      float m = fmaxf(fmaxf(val[0][2*c], val[0][2*c+1]),
                      fmaxf(val[1][2*c], val[1][2*c+1]));
      po[c] = fmaxf(m + bias, 0.f);
    }
    *(float4*)&outb[(size_t)oc*1024 + py*32 + px0] = o4;
  }
}

// ---------------- K2: stem conv2 (64->64, 32x32, pad1) + relu + pool -> h1 (b,64,16,16)
__global__ __launch_bounds__(256) void k2_stem2(
    const float* __restrict__ x1, const float* __restrict__ w1t,
    const float* __restrict__ b1, float* __restrict__ h1) {
  __shared__ float inp[8*34*34];   // 9248 floats, padded planes (chunk of 8 in-ch)
  int bx = blockIdx.x;
  int b  = (bx & 7)*32 + ((bx >> 3) & 31);
  int ocb = (bx >> 8) * 16;        // 4 groups of 16 out-channels
  int t = threadIdx.x;
  for (int i = t; i < 9248; i += 256) inp[i] = 0.f;
  int py = t >> 4, px = t & 15;
  float val[16][2][2];
  #pragma unroll
  for (int o = 0; o < 16; o++) { val[o][0][0]=0.f; val[o][0][1]=0.f; val[o][1][0]=0.f; val[o][1][1]=0.f; }
  const float* xb = x1 + (size_t)b*65536;
  for (int icc = 0; icc < 8; icc++) {
    __syncthreads();
    for (int i = t*4; i < 8192; i += 1024) {
      int icl = i >> 10;
      float4 v = *(const float4*)&xb[(size_t)(icc*8+icl)*1024 + (i & 1023)];
      float* dst = &inp[icl*1156 + (((i>>5)&31)+1)*34 + (i&31) + 1];
      dst[0]=v.x; dst[1]=v.y; dst[2]=v.z; dst[3]=v.w;
    }
    __syncthreads();
    for (int icl = 0; icl < 8; icl++) {
      int ic = icc*8 + icl;
      float wn[4][4];
      #pragma unroll
      for (int r = 0; r < 4; r++) {
        float2 v0 = *(const float2*)&inp[icl*1156 + (2*py+r)*34 + 2*px];
        float2 v1 = *(const float2*)&inp[icl*1156 + (2*py+r)*34 + 2*px + 2];
        wn[r][0]=v0.x; wn[r][1]=v0.y; wn[r][2]=v1.x; wn[r][3]=v1.y;
      }
      const float* wrow = w1t + (size_t)ic*576 + ocb;   // uniform address
      #pragma unroll
      for (int tap = 0; tap < 9; tap++) {
        const float4* wp = (const float4*)(wrow + tap*64);
        float4 wv0 = wp[0], wv1 = wp[1], wv2 = wp[2], wv3 = wp[3];
        float w16[16] = {wv0.x,wv0.y,wv0.z,wv0.w, wv1.x,wv1.y,wv1.z,wv1.w,
                         wv2.x,wv2.y,wv2.z,wv2.w, wv3.x,wv3.y,wv3.z,wv3.w};
        int dy = tap / 3, dx = tap - dy*3;
        #pragma unroll
        for (int oc = 0; oc < 16; oc++) {
          float w = w16[oc];
          #pragma unroll
          for (int r = 0; r < 2; r++)
            #pragma unroll
            for (int c = 0; c < 2; c++)
              val[oc][r][c] = fmaf(w, wn[r+dy][c+dx], val[oc][r][c]);
        }
      }
    }
  }
  float* hb = h1 + ((size_t)b*64 + ocb)*256;
  #pragma unroll
  for (int oc = 0; oc < 16; oc++) {
    float m = fmaxf(fmaxf(val[oc][0][0], val[oc][0][1]),
                    fmaxf(val[oc][1][0], val[oc][1][1]));
    hb[(size_t)oc*256 + py*16 + px] = fmaxf(m + b1[ocb+oc], 0.f);
  }
}

// ---------------- K3: blend qrep in native emb order (coalesced both sides) ----
__global__ __launch_bounds__(256) void k3_blend(
    const int* __restrict__ question, const float* __restrict__ emb1,
    const float* __restrict__ emb2, const float* __restrict__ soft,
    float* __restrict__ qrep, int iter) {
  int b = blockIdx.y;
  int part = blockIdx.x;          // 0..11, each covers 944 float4s
  int t = threadIdx.x;
  int idx[8]; float a[8];
  #pragma unroll
  for (int q = 0; q < 8; q++) { idx[q] = question[b*8+q]; a[q] = soft[iter*8+q]; }
  float* qb = qrep + (size_t)b*45184;
  #pragma unroll
  for (int i = 0; i < 4; i++) {
    int r = i*256 + t;
    int j4 = part*944 + r;
    if (r < 944 && j4 < 11296) {
      int j = j4*4;
      float4 acc = {0.f,0.f,0.f,0.f};
      if (j < 36928) {
        #pragma unroll
        for (int q = 0; q < 8; q++) {
          float4 v = *(const float4*)&emb1[(size_t)idx[q]*36928 + j];
          acc.x = fmaf(a[q], v.x, acc.x); acc.y = fmaf(a[q], v.y, acc.y);
          acc.z = fmaf(a[q], v.z, acc.z); acc.w = fmaf(a[q], v.w, acc.w);
        }
      } else {
        int jj = j - 36928;
        #pragma unroll
        for (int q = 0; q < 8; q++) {
          float4 v = *(const float4*)&emb2[(size_t)idx[q]*8256 + jj];
          acc.x = fmaf(a[q], v.x, acc.x); acc.y = fmaf(a[q], v.y, acc.y);
          acc.z = fmaf(a[q], v.z, acc.z); acc.w = fmaf(a[q], v.w, acc.w);
        }
      }
      *(float4*)&qb[j] = acc;
    }
  }
}

// ---------------- K4: fused module (blend -> proj -> per-sample conv) ----------
// one block per sample, 512 threads; dynamic LDS 141312 B; reads materialized qrep.
// Double-buffered staging: global->reg issued before compute, reg->LDS after barrier.
__global__ __launch_bounds__(512) void k4_module(
    const float* __restrict__ qrep, const float* __restrict__ soft,
    const float* __restrict__ h1, const float* __restrict__ h2,
    const float* __restrict__ h3, float* __restrict__ hout, int iter) {
  extern __shared__ float sm[];
  // phase A (words 0..20479): inp dbuf 2x8192 @0, pws dbuf 2x2048 @16384
  // phase B (words 0..35327): ppad 23040 @0, cwt dbuf 2x6144 @23040/@29184
  float* inpB0 = sm;
  float* inpB1 = sm + 8192;
  float* pwsB0 = sm + 16384;
  float* pwsB1 = sm + 18432;
  float* ppad  = sm;
  float* cwtB0 = sm + 23040;
  float* cwtB1 = sm + 29184;
  __shared__ float cbpb[128];  // cb[64] | pb[64]
  int b = blockIdx.x;
  int t = threadIdx.x;
  int og = t >> 6, pg = t & 63;
  int o8 = og*8, p4 = pg*4;
  int y = pg >> 2, x0 = (pg & 3)*4;
  size_t hb = (size_t)b*16384;
  const float* qb = qrep + (size_t)b*45184;

  if (t < 64) cbpb[t] = qb[36864 + t];
  else if (t < 128) cbpb[t] = qb[45120 + (t - 64)];

  float l1 = soft[24+iter*4+1];
  float l2 = (iter>=1) ? soft[24+iter*4+2] : 0.f;
  float l3 = (iter>=2) ? soft[24+iter*4+3] : 0.f;
  float r1 = soft[36+iter*4+1];
  float r2 = (iter>=1) ? soft[36+iter*4+2] : 0.f;
  float r3 = (iter>=2) ? soft[36+iter*4+3] : 0.f;

  // ---------- phase A: proj = pw @ [lhs; rhs], 4 chunks of 32 input-dims ----------
  float acc[8][4];
  #pragma unroll
  for (int i = 0; i < 8; i++)
    #pragma unroll
    for (int j = 0; j < 4; j++) acc[i][j] = 0.f;

  auto issueA = [&](int c, float4* v1, float4* v2, float4* v3, float4& pw) {
    #pragma unroll
    for (int p = 0; p < 4; p++) {
      int i4 = t + p*512;                 // 0..2047
      int dl = i4 >> 6;                   // 0..31
      int pix = (i4 & 63) * 4;
      int ch = (c & 1)*32 + dl;           // channel within h (d & 63)
      size_t off = hb + (size_t)ch*256 + pix;
      v1[p] = *(const float4*)&h1[off];
      if (iter >= 1) v2[p] = *(const float4*)&h2[off];
      if (iter >= 2) v3[p] = *(const float4*)&h3[off];
    }
    int o = t >> 3, dq = (t & 7)*4;
    pw = *(const float4*)&qb[36928 + o*128 + c*32 + dq];
  };
  auto writeA = [&](int c, float4* v1, float4* v2, float4* v3, float4& pw,
                    float* inpb, float* pwsb) {
    float c1 = (c >= 2) ? r1 : l1;
    float c2 = (c >= 2) ? r2 : l2;
    float c3 = (c >= 2) ? r3 : l3;
    #pragma unroll
    for (int p = 0; p < 4; p++) {
      int i4 = t + p*512;
      int dl = i4 >> 6;
      int pix = (i4 & 63) * 4;
      float4 v;
      v.x = c1*v1[p].x; v.y = c1*v1[p].y; v.z = c1*v1[p].z; v.w = c1*v1[p].w;
      if (iter >= 1) {
        v.x = fmaf(c2, v2[p].x, v.x); v.y = fmaf(c2, v2[p].y, v.y);
        v.z = fmaf(c2, v2[p].z, v.z); v.w = fmaf(c2, v2[p].w, v.w);
      }
      if (iter >= 2) {
        v.x = fmaf(c3, v3[p].x, v.x); v.y = fmaf(c3, v3[p].y, v.y);
        v.z = fmaf(c3, v3[p].z, v.z); v.w = fmaf(c3, v3[p].w, v.w);
      }
      *(float4*)&inpb[dl*256 + pix] = v;
    }
    int o = t >> 3, dq = (t & 7)*4;
    *(float4*)&pwsb[o*32 + dq] = pw;
  };

  {
    float4 a1[4], a2[4], a3[4], apw;
    issueA(0, a1, a2, a3, apw);
    writeA(0, a1, a2, a3, apw, inpB0, pwsB0);
  }
  __syncthreads();
  #pragma unroll
  for (int c = 0; c < 4; c++) {
    float4 b1v[4], b2v[4], b3v[4], bpw;
    if (c < 3) issueA(c+1, b1v, b2v, b3v, bpw);
    float* inpb = (c & 1) ? inpB1 : inpB0;
    float* pwsb = (c & 1) ? pwsB1 : pwsB0;
    for (int dl = 0; dl < 32; dl++) {
      float w[8];
      #pragma unroll
      for (int oi = 0; oi < 8; oi++) w[oi] = pwsb[(o8+oi)*32 + dl];
      float4 v = *(const float4*)&inpb[dl*256 + p4];
      float vv[4] = {v.x, v.y, v.z, v.w};
      #pragma unroll
      for (int oi = 0; oi < 8; oi++)
        #pragma unroll
        for (int pi = 0; pi < 4; pi++)
          acc[oi][pi] = fmaf(w[oi], vv[pi], acc[oi][pi]);
    }
    __syncthreads();
    if (c < 3) {
      writeA(c+1, b1v, b2v, b3v, bpw, (c & 1) ? inpB0 : inpB1,
             (c & 1) ? pwsB0 : pwsB1);
      __syncthreads();
    }
  }

  // ---------- proj (+pb) into padded LDS ----------
  float pbv[8];
  #pragma unroll
  for (int oi = 0; oi < 8; oi++) pbv[oi] = cbpb[64 + o8 + oi];
  for (int k = t; k < 23040; k += 512) ppad[k] = 0.f;
  __syncthreads();
  #pragma unroll
  for (int oi = 0; oi < 8; oi++)
    #pragma unroll
    for (int pi = 0; pi < 4; pi++)
      ppad[(o8+oi)*360 + (y+1)*20 + (x0+1) + pi] = acc[oi][pi] + pbv[oi];
  __syncthreads();

  // ---------- phase B: per-sample conv 64->64, 3x3, pad1, + cb, relu ----------
  float acc2[8][4];
  #pragma unroll
  for (int i = 0; i < 8; i++)
    #pragma unroll
    for (int j = 0; j < 4; j++) acc2[i][j] = 0.f;

  auto issueB = [&](int icc, float* r) {
    #pragma unroll
    for (int p = 0; p < 9; p++) {
      int i = t + p*512;               // 0..4607
      int oc = i / 72;
      int jj = i - oc*72;
      r[p] = qb[oc*576 + icc*72 + jj];
    }
  };
  auto writeB = [&](float* r, float* cwtb) {
    #pragma unroll
    for (int p = 0; p < 9; p++) {
      int i = t + p*512;
      int oc = i / 72;
      int jj = i - oc*72;
      int icl = jj / 9;
      int tap = jj - icl*9;
      cwtb[oc*96 + icl*12 + tap] = r[p];
    }
  };

  {
    float rg[9];
    issueB(0, rg);
    writeB(rg, cwtB0);
  }
  __syncthreads();
  #pragma unroll 1
  for (int icc = 0; icc < 8; icc++) {
    float rn[9];
    if (icc < 7) issueB(icc+1, rn);
    float* cwtb = (icc & 1) ? cwtB1 : cwtB0;
    for (int icl = 0; icl < 8; icl++) {
      int ic = icc*8 + icl;
      float wn[3][6];
      #pragma unroll
      for (int r = 0; r < 3; r++) {
        const float* pr = &ppad[ic*360 + (y+r)*20 + x0];
        float4 aa = *(const float4*)&pr[0];
        float2 bb2 = *(const float2*)&pr[4];
        wn[r][0]=aa.x; wn[r][1]=aa.y; wn[r][2]=aa.z; wn[r][3]=aa.w;
        wn[r][4]=bb2.x; wn[r][5]=bb2.y;
      }
      #pragma unroll
      for (int oi = 0; oi < 8; oi++) {
        const float* wp = &cwtb[(o8+oi)*96 + icl*12];
        float4 wA = *(const float4*)&wp[0];
        float4 wB = *(const float4*)&wp[4];
        float w8v = wp[8];
        float w9[9] = {wA.x,wA.y,wA.z,wA.w, wB.x,wB.y,wB.z,wB.w, w8v};
        #pragma unroll
        for (int dy = 0; dy < 3; dy++)
          #pragma unroll
          for (int dx = 0; dx < 3; dx++) {
            float w = w9[dy*3+dx];
            #pragma unroll
            for (int pi = 0; pi < 4; pi++)
              acc2[oi][pi] = fmaf(w, wn[dy][pi+dx], acc2[oi][pi]);
          }
      }
    }
    __syncthreads();
    if (icc < 7) {
      writeB(rn, (icc & 1) ? cwtB0 : cwtB1);
      __syncthreads();
    }
  }

  float* ho = hout + hb;
  #pragma unroll
  for (int oi = 0; oi < 8; oi++) {
    float cb = cbpb[o8 + oi];
    float4 s0;
    float* p0 = (float*)&s0;
    #pragma unroll
    for (int pi = 0; pi < 4; pi++) p0[pi] = fmaxf(acc2[oi][pi] + cb, 0.f);
    *(float4*)&ho[(size_t)(o8+oi)*256 + y*16 + x0] = s0;
  }
}

// ---------------- K5: proj512 + relu + pool -> f (b, 32768) ----------------
// dynamic LDS 83968 B
__global__ __launch_bounds__(256) void k5_proj(
    const float* __restrict__ h4, const float* __restrict__ wproj,
    const float* __restrict__ bproj, float* __restrict__ f) {
  extern __shared__ float sm[];
  float* hbuf = sm;            // 16384 (reused as cbuf)
  float* wt   = sm + 16384;    // [64][72] = 4608
  int bx = blockIdx.x;         // 2048; XCD-aware remap
  int b = (bx & 7)*32 + ((bx >> 3) & 31);
  int ocb = (bx >> 8) * 64;
  int t = threadIdx.x;
  int og = t >> 5, pg = t & 31, o8 = og*8, p8 = pg*8;
  for (int k = t*4; k < 16384; k += 1024)
    *(float4*)&hbuf[k] = *(const float4*)&h4[(size_t)b*16384 + k];
  for (int k = t; k < 4096; k += 256) {
    int ol = k >> 6, c = k & 63;
    wt[c*72 + ol] = wproj[(size_t)(ocb+ol)*64 + c];
  }
  __syncthreads();
  float acc[8][8];
  #pragma unroll
  for (int i = 0; i < 8; i++)
    #pragma unroll
    for (int j = 0; j < 8; j++) acc[i][j] = 0.f;
  for (int d = 0; d < 64; d++) {
    float4 wA = *(const float4*)&wt[d*72 + o8];
    float4 wB = *(const float4*)&wt[d*72 + o8 + 4];
    float4 vA = *(const float4*)&hbuf[d*256 + p8];
    float4 vB = *(const float4*)&hbuf[d*256 + p8 + 4];
    float wv[8] = {wA.x,wA.y,wA.z,wA.w, wB.x,wB.y,wB.z,wB.w};
    float vv[8] = {vA.x,vA.y,vA.z,vA.w, vB.x,vB.y,vB.z,vB.w};
    #pragma unroll
    for (int oi = 0; oi < 8; oi++)
      #pragma unroll
      for (int pi = 0; pi < 8; pi++)
        acc[oi][pi] = fmaf(wv[oi], vv[pi], acc[oi][pi]);
  }
  __syncthreads();
  float bv[8];
  #pragma unroll
  for (int oi = 0; oi < 8; oi++) bv[oi] = bproj[ocb + o8 + oi];
  #pragma unroll
  for (int oi = 0; oi < 8; oi++)
    #pragma unroll
    for (int pi = 0; pi < 8; pi++)
      hbuf[(o8+oi)*256 + p8 + pi] = fmaxf(acc[oi][pi] + bv[oi], 0.f);
  __syncthreads();
  float* fb = f + (size_t)b*32768 + (size_t)ocb*64;
  for (int k = t; k < 4096; k += 256) {
    int oc = k >> 6, pp = k & 63, pyy = pp >> 3, pxx = pp & 7;
    const float* cb_ = &hbuf[oc*256 + pyy*32 + pxx*2];
    float m = fmaxf(fmaxf(cb_[0], cb_[1]), fmaxf(cb_[16], cb_[17]));
    fb[(size_t)oc*64 + pp] = m;
  }
}

// ---------------- K6a: fc1 partial GEMM (K-split 32), [k][m] LDS layout ------
// grid 512 (2 blocks/CU, 8 waves/CU); register-prefetch double buffering;
// bank-swizzled staging writes: column (m + 8*((k>>3)&1)) & 127 -> 2-way max.
__global__ __launch_bounds__(256) void k6_fc1(
    const float* __restrict__ f, const float* __restrict__ w,
    float* __restrict__ part) {
  __shared__ float ab[32*132];
  __shared__ float bb[32*132];
  int bx = blockIdx.x;   // 512 = Ks*16 + Nt*2 + Mt
  int Mb = (bx & 1)*128;
  int Nb = ((bx >> 1) & 7)*128;
  int Ks = bx >> 4;      // 0..31
  int t = threadIdx.x;
  int og = t >> 4, pg = t & 15, m8 = og*8, n8 = pg*8;
  int kr4 = (t & 7)*4, mr4 = t >> 3;
  int wsh = (((t & 7) >> 1) & 1) * 8;   // = 8*((k>>3)&1) for this thread's 4 k's
  float acc[8][8];
  #pragma unroll
  for (int i = 0; i < 8; i++)
    #pragma unroll
    for (int j = 0; j < 8; j++) acc[i][j] = 0.f;

  float4 pa[4], pb[4];
  const float* frow = f + (size_t)(Mb + mr4)*32768 + Ks*1024 + kr4;
  const float* wrow = w + (size_t)(Nb + mr4)*32768 + Ks*1024 + kr4;

  auto issue = [&](int kc) {
    int k0 = kc*32;
    #pragma unroll
    for (int pass = 0; pass < 4; pass++) {
      pa[pass] = *(const float4*)&frow[(size_t)pass*32*32768 + k0];
      pb[pass] = *(const float4*)&wrow[(size_t)pass*32*32768 + k0];
    }
  };
  auto stage = [&]() {
    #pragma unroll
    for (int pass = 0; pass < 4; pass++) {
      int ms = ((pass*32 + mr4 + wsh) & 127);
      ab[(kr4+0)*132+ms] = pa[pass].x; ab[(kr4+1)*132+ms] = pa[pass].y;
      ab[(kr4+2)*132+ms] = pa[pass].z; ab[(kr4+3)*132+ms] = pa[pass].w;
      bb[(kr4+0)*132+ms] = pb[pass].x; bb[(kr4+1)*132+ms] = pb[pass].y;
      bb[(kr4+2)*132+ms] = pb[pass].z; bb[(kr4+3)*132+ms] = pb[pass].w;
    }
  };

  issue(0);
  stage();
  __syncthreads();
  for (int kc = 0; kc < 32; kc++) {
    if (kc < 31) issue(kc + 1);
    #pragma unroll 4
    for (int k = 0; k < 32; k++) {
      int s = ((k >> 3) & 1) * 8;
      float4 aA = *(const float4*)&ab[k*132 + ((m8 + s) & 127)];
      float4 aB = *(const float4*)&ab[k*132 + ((m8 + 4 + s) & 127)];
      float4 bA = *(const float4*)&bb[k*132 + ((n8 + s) & 127)];
      float4 bB = *(const float4*)&bb[k*132 + ((n8 + 4 + s) & 127)];
      float a8[8] = {aA.x,aA.y,aA.z,aA.w, aB.x,aB.y,aB.z,aB.w};
      float b8[8] = {bA.x,bA.y,bA.z,bA.w, bB.x,bB.y,bB.z,bB.w};
      #pragma unroll
      for (int mi = 0; mi < 8; mi++)
        #pragma unroll
        for (int ni = 0; ni < 8; ni++)
          acc[mi][ni] = fmaf(a8[mi], b8[ni], acc[mi][ni]);
    }
    if (kc < 31) {
      __syncthreads();
      stage();
      __syncthreads();
    }
  }

  float* pb_ = part + (size_t)Ks*262144;
  #pragma unroll
  for (int mi = 0; mi < 8; mi++) {
    float4 s0, s1;
    float* p0 = (float*)&s0; float* p1 = (float*)&s1;
    #pragma unroll
    for (int ni = 0; ni < 4; ni++) p0[ni] = acc[mi][ni];
    #pragma unroll
    for (int ni = 0; ni < 4; ni++) p1[ni] = acc[mi][4+ni];
    *(float4*)&pb_[(size_t)(Mb+m8+mi)*1024 + Nb + n8]     = s0;
    *(float4*)&pb_[(size_t)(Mb+m8+mi)*1024 + Nb + n8 + 4] = s1;
  }
}

// ---------------- K6b: reduce partials + bias + relu ----------------
__global__ __launch_bounds__(256) void k6b_reduce(
    const float* __restrict__ part, const float* __restrict__ bias,
    float* __restrict__ f2) {
  int j = blockIdx.x*256 + threadIdx.x;   // < 262144
  float s = bias[j & 1023];
  #pragma unroll
  for (int ks = 0; ks < 32; ks++) s += part[(size_t)ks*262144 + j];
  f2[j] = fmaxf(s, 0.f);
}

// ---------------- K7: fc2 ----------------
__global__ __launch_bounds__(256) void k7_fc2(
    const float* __restrict__ f2, const float* __restrict__ w2,
    const float* __restrict__ b2, float* __restrict__ out) {
  __shared__ float r0[256], r1[256];
  int b = blockIdx.x, t = threadIdx.x;
  float s0 = 0.f, s1 = 0.f;
  #pragma unroll
  for (int q = 0; q < 4; q++) {
    int k = q*256 + t;
    float v = f2[(size_t)b*1024 + k];
    s0 = fmaf(v, w2[k], s0);
    s1 = fmaf(v, w2[1024+k], s1);
  }
  r0[t] = s0; r1[t] = s1; __syncthreads();
  for (int s = 128; s > 0; s >>= 1) {
    if (t < s) { r0[t] += r0[t+s]; r1[t] += r1[t+s]; }
    __syncthreads();
  }
  if (t == 0) { out[b*2] = r0[0] + b2[0]; out[b*2+1] = r1[0] + b2[1]; }
}

// ---------------- host ----------------
extern "C" void kernel_launch(void* const* d_in, const int* in_sizes, int n_in,
                              void* d_out, int out_size, void* d_ws, size_t ws_size,
                              hipStream_t stream) {
  const float* image  = (const float*)d_in[0];
  const int*   question = (const int*)d_in[1];
  const float* emb1   = (const float*)d_in[2];
  const float* emb2   = (const float*)d_in[3];
  const float* alpha  = (const float*)d_in[4];
  const float* tau0   = (const float*)d_in[5];
  const float* tau1   = (const float*)d_in[6];
  const float* w_s0   = (const float*)d_in[7];
  const float* b_s0   = (const float*)d_in[8];
  const float* w_s1   = (const float*)d_in[9];
  const float* b_s1   = (const float*)d_in[10];
  const float* w_proj = (const float*)d_in[11];
  const float* b_proj = (const float*)d_in[12];
  const float* w_fc1  = (const float*)d_in[13];
  const float* b_fc1  = (const float*)d_in[14];
  const float* w_fc2  = (const float*)d_in[15];
  const float* b_fc2  = (const float*)d_in[16];
  float* out = (float*)d_out;

  // ws layout (floats):
  //   [0,64)                  softmaxes
  //   [64, 64+36864)          w1t
  //   big @36928 (16777216):  x1 (16.7M) -> qrep (11.57M) -> f[0,8.39M)+part[8.39M,16.78M)
  //   h  @36928+16777216:     h1..h4 (4 x 4194304); h1 region reused as f2 after k5
  if (ws_size < (size_t)134365440) return;  // visible failure if ws too small
  float* ws   = (float*)d_ws;
  float* soft = ws;
  float* w1t  = ws + 64;
  float* big  = ws + 36928;
  float* x1   = big;
  float* qrep = big;
  float* f    = big;
  float* part = big + 8388608;
  float* hbuf0 = ws + 36928 + 16777216;
  float* h[4] = { hbuf0, hbuf0 + 4194304, hbuf0 + 8388608, hbuf0 + 12582912 };
  float* f2   = hbuf0;   // h[0] dead after last k4

  hipFuncSetAttribute(reinterpret_cast<const void*>(k4_module),
                      hipFuncAttributeMaxDynamicSharedMemorySize, 141312);
  hipFuncSetAttribute(reinterpret_cast<const void*>(k5_proj),
                      hipFuncAttributeMaxDynamicSharedMemorySize, 83968);

  k0_softmax<<<1, 64, 0, stream>>>(alpha, tau0, tau1, soft);
  kpre_wt<<<144, 256, 0, stream>>>(w_s1, w1t);
  k1_stem1<<<512, 256, 0, stream>>>(image, w_s0, b_s0, x1);
  k2_stem2<<<1024, 256, 0, stream>>>(x1, w1t, b_s1, h[0]);
  for (int i = 0; i < 3; i++) {
    k3_blend<<<dim3(12, 256), 256, 0, stream>>>(question, emb1, emb2, soft, qrep, i);
    k4_module<<<256, 512, 141312, stream>>>(qrep, soft, h[0], h[1], h[2], h[i+1], i);
  }
  k5_proj<<<2048, 256, 83968, stream>>>(h[3], w_proj, b_proj, f);
  k6_fc1<<<512, 256, 0, stream>>>(f, w_fc1, part);
  k6b_reduce<<<1024, 256, 0, stream>>>(part, b_fc1, f2);
  k7_fc2<<<256, 256, 0, stream>>>(f2, w_fc2, b_fc2, out);
}